// Round 7
// baseline (1586.825 us; speedup 1.0000x reference)
//
#include <hip/hip_runtime.h>
#include <math.h>

// ---------------- dims / constants ----------------
#define EPS_Q 1e-4
#define TOLC  1e-3

// ws layout: doubles first
#define OFF_D22   0        // [32][32]
#define OFF_RINV  1024     // [32][32]
#define OFF_VR    2048     // [160][32]
#define OFF_T1    7168     // [160][32]
#define OFF_H     12288    // [160][160]
#define OFF_E     37888    // [64][64]
#define OFF_EI    41984    // [64][64]
#define OFF_TMP   46080    // [64][64]
#define OFF_TMP2  50176    // [64][64]
#define D_END     54272    // doubles
// float blob after doubles (byte offset 434176, 16B aligned):
// F_WXT  = 0      : Wx k-major f4-transposed [32 chunks][64 rows][4] = 8192 floats
// F_WYT  = 8192   : Wy k-major f4-transposed [32 chunks][32 rows][4] = 4096 floats
// F_D11  = 12288  : [32][32] strictly-lower, pre-scaled by K/Lam_i   = 1024
// F_WA   = 13312  : [32][96] rows [C1(64)|D12(32)] * (K/Lam_r)       = 3072
// K = 2*log2(e): chain state v lives in exp2 domain

// ================= kernel 1: H = X^T X + tol I  (parallel, 100 blocks) =================
__global__ __launch_bounds__(256, 1) void xtx(
    const float* __restrict__ X, double* __restrict__ wsd)
{
  double* H = wsd + OFF_H;
  int bi = blockIdx.x / 10, bj = blockIdx.x % 10;
  int i = bi*16 + (threadIdx.x >> 4);
  int j = bj*16 + (threadIdx.x & 15);
  double s = (i == j) ? TOLC : 0.0;
  for (int k = 0; k < 160; ++k) s += (double)X[k*160+i] * (double)X[k*160+j];
  H[i*160+j] = s;
}

// ================= kernel 2: fused prep (1 block x 1024 threads) =================
// prep1 (D22, R_cal^-1, vec_r, T1) widened 256->1024, then psi-add into H,
// then prep3 (E^-1 via fp32 GJ + 2x fp64 Newton, weight blob). Same algorithms
// and FP order as the 3-kernel version; only the thread stride changed.
__global__ __launch_bounds__(1024, 1) void prep_fused(
    const float* __restrict__ B2, const float* __restrict__ C2,
    const float* __restrict__ D12, const float* __restrict__ L,
    const float* __restrict__ U, const float* __restrict__ D21,
    const float* __restrict__ gam, const float* __restrict__ Y,
    double* __restrict__ wsd)
{
  __shared__ double aug1[32][65];   // prep1 GJ (fp64)
  __shared__ float  aug[64][130];   // prep3 GJ (fp32)
  __shared__ double sFacD[32];
  __shared__ float  sFacF[64];
  __shared__ int sPiv;
  const int tid = threadIdx.x;
  const double g = (double)gam[0];
  double* D22d = wsd + OFF_D22;

  // ---- prep1: D22 ----
  for (int idx = tid; idx < 1024; idx += 1024) {
    int i = idx >> 5, j = idx & 31;
    double s = (i == j) ? (g + 1.0) : 0.0;
    for (int k = 0; k < 32; ++k) s += (double)L[k*32+i] * (double)L[k*32+j];
    s += (double)U[i*32+j] - (double)U[j*32+i];
    D22d[idx] = s;
  }
  __syncthreads();
  // ---- prep1: R_cal into aug1 ----
  for (int idx = tid; idx < 1024; idx += 1024) {
    int i = idx >> 5, j = idx & 31;
    double s = (i == j) ? (-2.0 * g) : 0.0;
    s += D22d[i*32+j] + D22d[j*32+i];
    double q = 0.0;
    for (int k = 0; k < 32; ++k) q += D22d[k*32+i] * D22d[k*32+j];
    aug1[i][j] = s - EPS_Q * q;
    aug1[i][32+j] = (i == j) ? 1.0 : 0.0;
  }
  __syncthreads();
  // ---- prep1: pivoted GJ 32 ----
  for (int k = 0; k < 32; ++k) {
    if (tid < 64) {
      float mv = -1.f; int mi = k;
      if (tid < 32 && tid >= k) { mv = (float)fabs(aug1[tid][k]); mi = tid; }
      #pragma unroll
      for (int o = 32; o; o >>= 1) {
        float ov = __shfl_xor(mv, o); int oi = __shfl_xor(mi, o);
        if (ov > mv) { mv = ov; mi = oi; }
      }
      if (tid == 0) sPiv = mi;
    }
    __syncthreads();
    int p = sPiv;
    if (p != k) for (int c = tid; c < 64; c += 1024) { double t1 = aug1[k][c]; aug1[k][c] = aug1[p][c]; aug1[p][c] = t1; }
    __syncthreads();
    double pinv = 1.0 / aug1[k][k];
    if (tid < 32 && tid != k) sFacD[tid] = aug1[tid][k];
    __syncthreads();
    for (int c = tid; c < 64; c += 1024) aug1[k][c] *= pinv;
    __syncthreads();
    for (int idx = tid; idx < 2048; idx += 1024) {
      int r = idx >> 6, c = idx & 63;
      if (r != k) aug1[r][c] -= sFacD[r] * aug1[k][c];
    }
    __syncthreads();
  }
  double* Rinv = wsd + OFF_RINV;
  for (int idx = tid; idx < 1024; idx += 1024) Rinv[idx] = aug1[idx >> 5][32 + (idx & 31)];

  // ---- prep1: vec_r ----
  double* vr = wsd + OFF_VR;
  for (int idx = tid; idx < 64*32; idx += 1024) {
    int p = idx >> 5, k = idx & 31;
    double q = 0.0;
    for (int m = 0; m < 32; ++m) q += D22d[m*32+k] * (double)C2[m*64+p];
    vr[p*32+k] = (double)C2[k*64+p] - EPS_Q * q;
  }
  for (int idx = tid; idx < 32*32; idx += 1024) {
    int p = idx >> 5, k = idx & 31;
    double q = 0.0;
    for (int m = 0; m < 32; ++m) q += D22d[m*32+k] * (double)D21[m*32+p];
    vr[(64+p)*32+k] = (double)D21[k*32+p] - EPS_Q * q - (double)D12[p*32+k];
  }
  for (int idx = tid; idx < 64*32; idx += 1024) {
    int p = idx >> 5, k = idx & 31;
    vr[(96+p)*32+k] = (double)B2[p*32+k];
  }
  __syncthreads();
  // ---- prep1: T1 = vr @ Rinv ----
  double* T1 = wsd + OFF_T1;
  for (int idx = tid; idx < 160*32; idx += 1024) {
    int p = idx >> 5, k2 = idx & 31;
    double s = 0.0;
    for (int k = 0; k < 32; ++k) s += vr[p*32+k] * Rinv[k*32+k2];
    T1[idx] = s;
  }
  __syncthreads();
  // ---- psi-add: H += psi_r - psi_q (H already = X^T X + tol I from xtx) ----
  for (int idx = tid; idx < 25600; idx += 1024) {
    int i = idx / 160, j = idx % 160;
    double* H = wsd + OFF_H;
    double pr = 0.0;
    for (int k = 0; k < 32; ++k) pr += T1[i*32+k] * vr[j*32+k];
    double s = H[i*160+j] + pr;
    if (i < 96 && j < 96) {
      double vq = 0.0;
      for (int k = 0; k < 32; ++k) {
        double a = (i < 64) ? (double)C2[k*64+i] : (double)D21[k*32+(i-64)];
        double b = (j < 64) ? (double)C2[k*64+j] : (double)D21[k*32+(j-64)];
        vq += a*b;
      }
      s += EPS_Q * vq;
    }
    H[i*160+j] = s;
  }
  __syncthreads();

  // ---- prep3: E build ----
  double* H   = wsd + OFF_H;
  double* Ed  = wsd + OFF_E;
  double* Ei  = wsd + OFF_EI;
  double* Tm  = wsd + OFF_TMP;
  double* Tm2 = wsd + OFF_TMP2;
  float* fb = (float*)(wsd + D_END);
  const double KS = 2.8853900817779268;   // 2*log2(e)

  for (int idx = tid; idx < 4096; idx += 1024) {
    int i = idx >> 6, j = idx & 63;
    double e = 0.5*(H[i*160+j] + H[(96+i)*160+(96+j)] + (double)Y[i*64+j] - (double)Y[j*64+i]);
    Ed[idx] = e;
    aug[i][j] = (float)e;
    aug[i][64+j] = (i == j) ? 1.f : 0.f;
  }
  __syncthreads();
  // ---- prep3: pivoted GJ 64 (fp32) ----
  for (int k = 0; k < 64; ++k) {
    if (tid < 64) {
      float mv = -1.f; int mi = k;
      if (tid >= k) { mv = fabsf(aug[tid][k]); mi = tid; }
      #pragma unroll
      for (int o = 32; o; o >>= 1) {
        float ov = __shfl_xor(mv, o); int oi = __shfl_xor(mi, o);
        if (ov > mv) { mv = ov; mi = oi; }
      }
      if (tid == 0) sPiv = mi;
    }
    __syncthreads();
    int p = sPiv;
    if (p != k) for (int c = tid; c < 128; c += 1024) { float t1 = aug[k][c]; aug[k][c] = aug[p][c]; aug[p][c] = t1; }
    __syncthreads();
    float pinv = 1.0f / aug[k][k];
    if (tid < 64 && tid != k) sFacF[tid] = aug[tid][k];
    __syncthreads();
    for (int c = tid; c < 128; c += 1024) aug[k][c] *= pinv;
    __syncthreads();
    for (int idx = tid; idx < 64*128; idx += 1024) {
      int r = idx >> 7, c = idx & 127;
      if (r != k) aug[r][c] -= sFacF[r] * aug[k][c];
    }
    __syncthreads();
  }
  for (int idx = tid; idx < 4096; idx += 1024) Ei[idx] = (double)aug[idx >> 6][64 + (idx & 63)];
  __syncthreads();
  // ---- prep3: 2x fp64 Newton ----
  for (int it = 0; it < 2; ++it) {
    for (int idx = tid; idx < 4096; idx += 1024) {
      int i = idx >> 6, j = idx & 63;
      double s = (i == j) ? 2.0 : 0.0;
      for (int k = 0; k < 64; ++k) s -= Ed[i*64+k] * Ei[k*64+j];
      Tm[idx] = s;
    }
    __syncthreads();
    for (int idx = tid; idx < 4096; idx += 1024) {
      int i = idx >> 6, j = idx & 63;
      double s = 0.0;
      for (int k = 0; k < 64; ++k) s += Ei[i*64+k] * Tm[k*64+j];
      Tm2[idx] = s;
    }
    __syncthreads();
    for (int idx = tid; idx < 4096; idx += 1024) Ei[idx] = Tm2[idx];
    __syncthreads();
  }
  // ---- prep3: weight blob ----
  // WxT: k-major f4-transposed [32 chunks][64 rows][4]
  for (int idx = tid; idx < 64*128; idx += 1024) {
    int r = idx >> 7, col = idx & 127;
    double s = 0.0;
    if (col < 64)       { for (int k = 0; k < 64; ++k) s += Ei[r*64+k] * H[(96+k)*160 + col]; }
    else if (col < 96)  { int jj = col-64; for (int k = 0; k < 64; ++k) s += Ei[r*64+k] * H[(96+k)*160 + 64 + jj]; }
    else                { int jj = col-96; for (int k = 0; k < 64; ++k) s += Ei[r*64+k] * (double)B2[k*32+jj]; }
    fb[((col >> 2)*64 + r)*4 + (col & 3)] = (float)s;
  }
  // WyT: k-major f4-transposed [32 chunks][32 rows][4]; cols [C2(64)|D21(32)|D22(32)]
  for (int idx = tid; idx < 32*128; idx += 1024) {
    int r = idx >> 7, col = idx & 127;
    float v;
    if (col < 64)      v = C2[r*64 + col];
    else if (col < 96) v = D21[r*32 + (col-64)];
    else               v = (float)D22d[r*32 + (col-96)];
    fb[8192 + ((col >> 2)*32 + r)*4 + (col & 3)] = v;
  }
  // D11' (strict lower, scaled by K/Lam_i) @ 12288
  for (int idx = tid; idx < 1024; idx += 1024) {
    int i = idx >> 5, j = idx & 31;
    double li = 2.0 / H[(64+i)*160 + 64+i];
    fb[12288 + idx] = (j < i) ? (float)(-H[(64+i)*160 + 64+j] * li * KS) : 0.f;
  }
  // Wa = [C1 | D12] * (K/Lam_r), row-major [32][96] @ 13312
  for (int idx = tid; idx < 32*96; idx += 1024) {
    int r = idx / 96, j = idx % 96;
    double li = 2.0 / H[(64+r)*160 + 64+r];
    double v = (j < 64) ? (-H[(64+r)*160 + j] * li) : ((double)D12[r*32 + (j-64)] * li);
    fb[13312 + idx] = (float)(v * KS);
  }
}

// ================= main recurrence (byte-identical to round 6: 847us proven) =================
__device__ __forceinline__ float frcp(float x) {
#if __has_builtin(__builtin_amdgcn_rcpf)
  return __builtin_amdgcn_rcpf(x);
#else
  return 1.0f / x;
#endif
}
__device__ __forceinline__ float hsum4(float4 a) { return (a.x + a.y) + (a.z + a.w); }

// E=1: wave per element, 2048 waves = 2 waves/SIMD. Wx pinned to the unified
// VGPR/AGPR file (R6: VALU reads AGPRs directly on gfx950; VGPR_Count=128 is
// arch-VGPRs only, no spill: WRITE_SIZE clean). R6 RESULT: LDS traffic halved,
// perf UNCHANGED (847us) -> LDS BW is NOT the wall; VALU issue + serial-chain
// latency exposure is (VALUBusy 73.5%, ~26% both-waves-stalled).
#define PIN(x) asm volatile("" : "+v"(x))
__global__ __launch_bounds__(256, 1) void ren_main(
    const float* __restrict__ u_in, const float* __restrict__ x0,
    const double* __restrict__ wsd, float* __restrict__ out)
{
  __shared__ __align__(16) float sW[8192];     // Wy[32ch][32r]f4 | WaT[24ch][32r]f4 | Wx ch28-31 [4][64r]f4
  __shared__ __align__(16) float sXU[4][132];  // per wave: x(64)|w(32)|u(32)|pad(4)
  const float* fb = (const float*)(wsd + D_END);
  const int tid = threadIdx.x;
  {
    const float4* g4 = (const float4*)fb;
    float4* s4 = (float4*)sW;
    for (int i = tid; i < 1024; i += 256) s4[i] = g4[2048 + i];   // Wy (fb f4 2048..3071)
    for (int i = tid; i < 768; i += 256) {                        // Wa: [32][24] -> [24][32]
      int r2 = i / 24, ch = i % 24;
      s4[1024 + ch*32 + r2] = g4[3328 + i];                       // fb f4 3328..4095
    }
    if (tid < 256) s4[1792 + tid] = g4[1792 + tid];               // Wx chunks 28-31 (fb f4 1792..2047)
  }
  const int wv = tid >> 6, l = tid & 63;
  const int r = l & 31, lh = l >> 5;
  const int e = blockIdx.x * 4 + wv;           // this wave's element
  float* xu = &sXU[wv][0];

  // Wx chunks 0..27, row l: 28 f4 = 112 regs (loaded once, coalesced, asm-pinned)
  float4 wx[28];
  {
    const float4* WxG = (const float4*)fb;
    #pragma unroll
    for (int c = 0; c < 28; ++c) wx[c] = WxG[(c << 6) + l];
  }
  // D11' row r (strict lower, K/Lam-scaled): 32 regs, asm-pinned
  float d11[32];
  {
    const float4* DG = (const float4*)(fb + 12288);
    #pragma unroll
    for (int c = 0; c < 8; ++c) {
      float4 dv = DG[r*8 + c];
      d11[4*c+0] = dv.x; d11[4*c+1] = dv.y; d11[4*c+2] = dv.z; d11[4*c+3] = dv.w;
    }
  }
  // Opaque-pin (scalar ties only): forbids remat/load-sinking.
  #pragma unroll
  for (int c = 0; c < 28; ++c) {
    PIN(wx[c].x); PIN(wx[c].y); PIN(wx[c].z); PIN(wx[c].w);
  }
  #pragma unroll
  for (int j = 0; j < 32; ++j) PIN(d11[j]);

  // x0 and u(t=0)
  xu[l] = x0[(size_t)e*64 + l];
  xu[96 + r] = u_in[(size_t)e*8192 + r];       // both halves write same value
  __syncthreads();   // weights staged (once, outside t-loop)

  const float4* xu4  = (const float4*)xu;      // 33 f4: x 0-15 | w 16-23 | u 24-31
  const float4* WyT4 = (const float4*)sW;              // [(ch<<5)+r]
  const float4* WaT4 = (const float4*)sW + 1024;       // [(lh*12+c)*32 + r]
  const float4* sWx4 = (const float4*)sW + 1792;       // [(c-28)*64 + l]
  const float* uG = u_in + (size_t)e * 8192;
  float* oG = out + (size_t)e * 8192;

#define FMA4(A, W, XV) \
  A.x = fmaf(W.x, XV.x, A.x); A.y = fmaf(W.y, XV.y, A.y); \
  A.z = fmaf(W.z, XV.z, A.z); A.w = fmaf(W.w, XV.w, A.w);

  for (int t = 0; t < 256; ++t) {
    const int tn = (t < 255) ? (t + 1) : 255;
    float unext = uG[tn*32 + r];               // prefetch u_{t+1}
    // ---- A: a_r (K-scaled), k-split across halves, combine via shfl ----
    float4 sA = make_float4(0.f, 0.f, 0.f, 0.f);
    #pragma unroll
    for (int c = 0; c < 12; ++c) {
      int ch = lh*12 + c;
      int xi = (ch < 16) ? ch : (ch + 8);      // u chunks at f4 24..31
      float4 xv = xu4[xi]; float4 wv4 = WaT4[ch*32 + r];
      FMA4(sA, wv4, xv)
    }
    float a = hsum4(sA);
    a += __shfl_xor(a, 32);                    // all 64 lanes: K*a for row r
    // ---- X partial: x chunks (regs) + u chunks (regs 24-27, LDS 28-31) ----
    float4 P4 = make_float4(0.f, 0.f, 0.f, 0.f);
    #pragma unroll
    for (int c = 0; c < 16; ++c) { float4 xv = xu4[c]; FMA4(P4, wx[c], xv) }
    #pragma unroll
    for (int c = 24; c < 28; ++c) { float4 xv = xu4[c]; FMA4(P4, wx[c], xv) }
    #pragma unroll
    for (int c = 28; c < 32; ++c) { float4 xv = xu4[c]; float4 wv4 = sWx4[((c - 28) << 6) + l]; FMA4(P4, wv4, xv) }
    // ---- Y partial: D22.u chunks (lh0: 24..27, lh1: 28..31) ----
    float4 Q4 = make_float4(0.f, 0.f, 0.f, 0.f);
    #pragma unroll
    for (int c = 0; c < 4; ++c) {
      int ch = 24 + lh*4 + c;
      float4 xv = xu4[ch]; float4 wv4 = WyT4[(ch << 5) + r];
      FMA4(Q4, wv4, xv)
    }
    // ---- serial tanh forward-substitution (6-op step, exp2 domain) ----
    float v = a;
    #pragma unroll
    for (int j = 0; j < 31; ++j) {
      float E = __builtin_exp2f(v);
      float w = fmaf(-2.f, frcp(E + 1.f), 1.f);
      float b = __int_as_float(__builtin_amdgcn_readlane(__float_as_int(w), j));
      v = fmaf(d11[j], b, v);
    }
    float Ef = __builtin_exp2f(v);
    float myw = fmaf(-2.f, frcp(Ef + 1.f), 1.f);
    xu[64 + r] = myw;                          // both halves same value
    // ---- X final: w chunks 16..23 (regs), then store xn ----
    #pragma unroll
    for (int c = 16; c < 24; ++c) { float4 xv = xu4[c]; FMA4(P4, wx[c], xv) }
    xu[l] = hsum4(P4);                         // xn row l
    // ---- Y final: chunks lh*12 .. lh*12+11 (xn + w), combine via shfl ----
    #pragma unroll
    for (int c = 0; c < 12; ++c) {
      int ch = lh*12 + c;
      float4 xv = xu4[ch]; float4 wv4 = WyT4[(ch << 5) + r];
      FMA4(Q4, wv4, xv)
    }
    float y = hsum4(Q4);
    y += __shfl_xor(y, 32);
    if (l < 32) oG[t*32 + l] = y;              // contiguous 128 B
    xu[96 + r] = unext;                        // u_{t+1} (u_t fully consumed)
  }
#undef FMA4
}
#undef PIN

// ================= launch =================
extern "C" void kernel_launch(void* const* d_in, const int* in_sizes, int n_in,
                              void* d_out, int out_size, void* d_ws, size_t ws_size,
                              hipStream_t stream)
{
  const float* u_in = (const float*)d_in[0];
  const float* x0   = (const float*)d_in[1];
  const float* X    = (const float*)d_in[2];
  const float* Y    = (const float*)d_in[3];
  const float* B2   = (const float*)d_in[4];
  const float* C2   = (const float*)d_in[5];
  const float* D12  = (const float*)d_in[6];
  const float* L    = (const float*)d_in[7];   // D22_L
  const float* U    = (const float*)d_in[8];   // D22_U
  const float* D21  = (const float*)d_in[9];
  const float* gam  = (const float*)d_in[10];
  double* wsd = (double*)d_ws;
  float* out = (float*)d_out;

  hipLaunchKernelGGL(xtx, dim3(100), dim3(256), 0, stream, X, wsd);
  hipLaunchKernelGGL(prep_fused, dim3(1), dim3(1024), 0, stream,
                     B2, C2, D12, L, U, D21, gam, Y, wsd);
  hipLaunchKernelGGL(ren_main, dim3(512), dim3(256), 0, stream, u_in, x0, wsd, out);
}

// Round 8
// 1358.001 us; speedup vs baseline: 1.1685x; 1.1685x over previous
//
#include <hip/hip_runtime.h>
#include <math.h>

// ---------------- dims / constants ----------------
#define EPS_Q 1e-4
#define TOLC  1e-3

// ws layout: doubles first
#define OFF_D22   0        // [32][32]
#define OFF_RINV  1024     // [32][32]
#define OFF_VR    2048     // [160][32]
#define OFF_T1    7168     // [160][32]
#define OFF_H     12288    // [160][160]
#define OFF_E     37888    // [64][64]
#define OFF_EI    41984    // [64][64]
#define OFF_TMP   46080    // [64][64]
#define OFF_TMP2  50176    // [64][64]
#define D_END     54272    // doubles
// float blob after doubles (byte offset 434176, 16B aligned):
// F_WXT  = 0      : Wx k-major f4-transposed [32 chunks][64 rows][4] = 8192 floats
// F_WYT  = 8192   : Wy k-major f4-transposed [32 chunks][32 rows][4] = 4096 floats
// F_D11  = 12288  : [32][32] strictly-lower, pre-scaled by K/Lam_i   = 1024
// F_WA   = 13312  : [32][96] rows [C1(64)|D12(32)] * (K/Lam_r)       = 3072
// K = 2*log2(e): chain state v lives in exp2 domain

// ================= prep 1: D22, R_cal^-1, vec_r, T1 (1024 thr: R7 lesson — widen,
// don't fuse; fusing psi into a 1-block kernel serialized 100-block work) =================
__global__ __launch_bounds__(1024, 1) void prep1(
    const float* __restrict__ B2, const float* __restrict__ C2,
    const float* __restrict__ D12, const float* __restrict__ L,
    const float* __restrict__ U, const float* __restrict__ D21,
    const float* __restrict__ gam, double* __restrict__ wsd)
{
  __shared__ double aug[32][65];
  __shared__ double sFac[32];
  __shared__ int sPiv;
  const int tid = threadIdx.x;
  const double g = (double)gam[0];
  double* D22d = wsd + OFF_D22;

  for (int idx = tid; idx < 1024; idx += 1024) {
    int i = idx >> 5, j = idx & 31;
    double s = (i == j) ? (g + 1.0) : 0.0;
    for (int k = 0; k < 32; ++k) s += (double)L[k*32+i] * (double)L[k*32+j];
    s += (double)U[i*32+j] - (double)U[j*32+i];
    D22d[idx] = s;
  }
  __syncthreads();
  for (int idx = tid; idx < 1024; idx += 1024) {
    int i = idx >> 5, j = idx & 31;
    double s = (i == j) ? (-2.0 * g) : 0.0;
    s += D22d[i*32+j] + D22d[j*32+i];
    double q = 0.0;
    for (int k = 0; k < 32; ++k) q += D22d[k*32+i] * D22d[k*32+j];
    aug[i][j] = s - EPS_Q * q;
    aug[i][32+j] = (i == j) ? 1.0 : 0.0;
  }
  __syncthreads();
  for (int k = 0; k < 32; ++k) {
    if (tid < 64) {
      float mv = -1.f; int mi = k;
      if (tid < 32 && tid >= k) { mv = (float)fabs(aug[tid][k]); mi = tid; }
      #pragma unroll
      for (int o = 32; o; o >>= 1) {
        float ov = __shfl_xor(mv, o); int oi = __shfl_xor(mi, o);
        if (ov > mv) { mv = ov; mi = oi; }
      }
      if (tid == 0) sPiv = mi;
    }
    __syncthreads();
    int p = sPiv;
    if (p != k) for (int c = tid; c < 64; c += 1024) { double t1 = aug[k][c]; aug[k][c] = aug[p][c]; aug[p][c] = t1; }
    __syncthreads();
    double pinv = 1.0 / aug[k][k];
    if (tid < 32 && tid != k) sFac[tid] = aug[tid][k];
    __syncthreads();
    for (int c = tid; c < 64; c += 1024) aug[k][c] *= pinv;
    __syncthreads();
    for (int idx = tid; idx < 2048; idx += 1024) {
      int r = idx >> 6, c = idx & 63;
      if (r != k) aug[r][c] -= sFac[r] * aug[k][c];
    }
    __syncthreads();
  }
  double* Rinv = wsd + OFF_RINV;
  for (int idx = tid; idx < 1024; idx += 1024) Rinv[idx] = aug[idx >> 5][32 + (idx & 31)];

  double* vr = wsd + OFF_VR;
  for (int idx = tid; idx < 64*32; idx += 1024) {
    int p = idx >> 5, k = idx & 31;
    double q = 0.0;
    for (int m = 0; m < 32; ++m) q += D22d[m*32+k] * (double)C2[m*64+p];
    vr[p*32+k] = (double)C2[k*64+p] - EPS_Q * q;
  }
  for (int idx = tid; idx < 32*32; idx += 1024) {
    int p = idx >> 5, k = idx & 31;
    double q = 0.0;
    for (int m = 0; m < 32; ++m) q += D22d[m*32+k] * (double)D21[m*32+p];
    vr[(64+p)*32+k] = (double)D21[k*32+p] - EPS_Q * q - (double)D12[p*32+k];
  }
  for (int idx = tid; idx < 64*32; idx += 1024) {
    int p = idx >> 5, k = idx & 31;
    vr[(96+p)*32+k] = (double)B2[p*32+k];
  }
  __syncthreads();
  double* T1 = wsd + OFF_T1;
  for (int idx = tid; idx < 160*32; idx += 1024) {
    int p = idx >> 5, k2 = idx & 31;
    double s = 0.0;
    for (int k = 0; k < 32; ++k) s += vr[p*32+k] * Rinv[k*32+k2];
    T1[idx] = s;
  }
}

// ================= prep 2: H = X^T X + tol I + psi_r - psi_q (100 blocks) =================
__global__ __launch_bounds__(256, 1) void prep2(
    const float* __restrict__ X, const float* __restrict__ C2,
    const float* __restrict__ D21, double* __restrict__ wsd)
{
  const double* vr = wsd + OFF_VR;
  const double* T1 = wsd + OFF_T1;
  double* H = wsd + OFF_H;
  int bi = blockIdx.x / 10, bj = blockIdx.x % 10;
  int i = bi*16 + (threadIdx.x >> 4);
  int j = bj*16 + (threadIdx.x & 15);
  double s = (i == j) ? TOLC : 0.0;
  for (int k = 0; k < 160; ++k) s += (double)X[k*160+i] * (double)X[k*160+j];
  double pr = 0.0;
  for (int k = 0; k < 32; ++k) pr += T1[i*32+k] * vr[j*32+k];
  s += pr;
  if (i < 96 && j < 96) {
    double vq = 0.0;
    for (int k = 0; k < 32; ++k) {
      double a = (i < 64) ? (double)C2[k*64+i] : (double)D21[k*32+(i-64)];
      double b = (j < 64) ? (double)C2[k*64+j] : (double)D21[k*32+(j-64)];
      vq += a*b;
    }
    s += EPS_Q * vq;
  }
  H[i*160+j] = s;
}

// ================= prep 3: E^-1 (GJ fp32 + 2x fp64 Newton), weight blob =================
__global__ __launch_bounds__(1024, 1) void prep3(
    const float* __restrict__ Y, const float* __restrict__ B2,
    const float* __restrict__ C2, const float* __restrict__ D12,
    const float* __restrict__ D21, double* __restrict__ wsd)
{
  __shared__ float aug[64][130];
  __shared__ float sFac[64];
  __shared__ int sPiv;
  const int tid = threadIdx.x;
  double* H   = wsd + OFF_H;
  double* Ed  = wsd + OFF_E;
  double* Ei  = wsd + OFF_EI;
  double* Tm  = wsd + OFF_TMP;
  double* Tm2 = wsd + OFF_TMP2;
  double* D22d = wsd + OFF_D22;
  float* fb = (float*)(wsd + D_END);
  const double KS = 2.8853900817779268;   // 2*log2(e)

  for (int idx = tid; idx < 4096; idx += 1024) {
    int i = idx >> 6, j = idx & 63;
    double e = 0.5*(H[i*160+j] + H[(96+i)*160+(96+j)] + (double)Y[i*64+j] - (double)Y[j*64+i]);
    Ed[idx] = e;
    aug[i][j] = (float)e;
    aug[i][64+j] = (i == j) ? 1.f : 0.f;
  }
  __syncthreads();
  for (int k = 0; k < 64; ++k) {
    if (tid < 64) {
      float mv = -1.f; int mi = k;
      if (tid >= k) { mv = fabsf(aug[tid][k]); mi = tid; }
      #pragma unroll
      for (int o = 32; o; o >>= 1) {
        float ov = __shfl_xor(mv, o); int oi = __shfl_xor(mi, o);
        if (ov > mv) { mv = ov; mi = oi; }
      }
      if (tid == 0) sPiv = mi;
    }
    __syncthreads();
    int p = sPiv;
    if (p != k) for (int c = tid; c < 128; c += 1024) { float t1 = aug[k][c]; aug[k][c] = aug[p][c]; aug[p][c] = t1; }
    __syncthreads();
    float pinv = 1.0f / aug[k][k];
    if (tid < 64 && tid != k) sFac[tid] = aug[tid][k];
    __syncthreads();
    for (int c = tid; c < 128; c += 1024) aug[k][c] *= pinv;
    __syncthreads();
    for (int idx = tid; idx < 64*128; idx += 1024) {
      int r = idx >> 7, c = idx & 127;
      if (r != k) aug[r][c] -= sFac[r] * aug[k][c];
    }
    __syncthreads();
  }
  for (int idx = tid; idx < 4096; idx += 1024) Ei[idx] = (double)aug[idx >> 6][64 + (idx & 63)];
  __syncthreads();
  for (int it = 0; it < 2; ++it) {
    for (int idx = tid; idx < 4096; idx += 1024) {
      int i = idx >> 6, j = idx & 63;
      double s = (i == j) ? 2.0 : 0.0;
      for (int k = 0; k < 64; ++k) s -= Ed[i*64+k] * Ei[k*64+j];
      Tm[idx] = s;
    }
    __syncthreads();
    for (int idx = tid; idx < 4096; idx += 1024) {
      int i = idx >> 6, j = idx & 63;
      double s = 0.0;
      for (int k = 0; k < 64; ++k) s += Ei[i*64+k] * Tm[k*64+j];
      Tm2[idx] = s;
    }
    __syncthreads();
    for (int idx = tid; idx < 4096; idx += 1024) Ei[idx] = Tm2[idx];
    __syncthreads();
  }
  // WxT: k-major f4-transposed [32 chunks][64 rows][4]
  for (int idx = tid; idx < 64*128; idx += 1024) {
    int r = idx >> 7, col = idx & 127;
    double s = 0.0;
    if (col < 64)       { for (int k = 0; k < 64; ++k) s += Ei[r*64+k] * H[(96+k)*160 + col]; }
    else if (col < 96)  { int jj = col-64; for (int k = 0; k < 64; ++k) s += Ei[r*64+k] * H[(96+k)*160 + 64 + jj]; }
    else                { int jj = col-96; for (int k = 0; k < 64; ++k) s += Ei[r*64+k] * (double)B2[k*32+jj]; }
    fb[((col >> 2)*64 + r)*4 + (col & 3)] = (float)s;
  }
  // WyT: k-major f4-transposed [32 chunks][32 rows][4]; cols [C2(64)|D21(32)|D22(32)]
  for (int idx = tid; idx < 32*128; idx += 1024) {
    int r = idx >> 7, col = idx & 127;
    float v;
    if (col < 64)      v = C2[r*64 + col];
    else if (col < 96) v = D21[r*32 + (col-64)];
    else               v = (float)D22d[r*32 + (col-96)];
    fb[8192 + ((col >> 2)*32 + r)*4 + (col & 3)] = v;
  }
  // D11' (strict lower, scaled by K/Lam_i) @ 12288  -- chain runs in exp2 domain
  for (int idx = tid; idx < 1024; idx += 1024) {
    int i = idx >> 5, j = idx & 31;
    double li = 2.0 / H[(64+i)*160 + 64+i];
    fb[12288 + idx] = (j < i) ? (float)(-H[(64+i)*160 + 64+j] * li * KS) : 0.f;
  }
  // Wa = [C1 | D12] * (K/Lam_r), row-major [32][96] @ 13312
  for (int idx = tid; idx < 32*96; idx += 1024) {
    int r = idx / 96, j = idx % 96;
    double li = 2.0 / H[(64+r)*160 + 64+r];
    double v = (j < 64) ? (-H[(64+r)*160 + j] * li) : ((double)D12[r*32 + (j-64)] * li);
    fb[13312 + idx] = (float)(v * KS);
  }
}

// ================= main recurrence (byte-identical to R6/R7: 831-847us proven) =================
__device__ __forceinline__ float frcp(float x) {
#if __has_builtin(__builtin_amdgcn_rcpf)
  return __builtin_amdgcn_rcpf(x);
#else
  return 1.0f / x;
#endif
}
__device__ __forceinline__ float hsum4(float4 a) { return (a.x + a.y) + (a.z + a.w); }

// E=1: wave per element, 2048 waves = 2 waves/SIMD. Wx pinned to the unified
// VGPR/AGPR file (R6: VALU reads AGPRs directly on gfx950; VGPR_Count=128 is
// arch-VGPRs only, no spill). R6 RESULT: LDS traffic halved, perf UNCHANGED
// -> LDS BW is NOT the wall; VALU issue + serial-chain latency exposure is
// (VALUBusy ~76%). Next structural lever: 2-wave-per-element split (4 waves/SIMD).
#define PIN(x) asm volatile("" : "+v"(x))
__global__ __launch_bounds__(256, 1) void ren_main(
    const float* __restrict__ u_in, const float* __restrict__ x0,
    const double* __restrict__ wsd, float* __restrict__ out)
{
  __shared__ __align__(16) float sW[8192];     // Wy[32ch][32r]f4 | WaT[24ch][32r]f4 | Wx ch28-31 [4][64r]f4
  __shared__ __align__(16) float sXU[4][132];  // per wave: x(64)|w(32)|u(32)|pad(4)
  const float* fb = (const float*)(wsd + D_END);
  const int tid = threadIdx.x;
  {
    const float4* g4 = (const float4*)fb;
    float4* s4 = (float4*)sW;
    for (int i = tid; i < 1024; i += 256) s4[i] = g4[2048 + i];   // Wy (fb f4 2048..3071)
    for (int i = tid; i < 768; i += 256) {                        // Wa: [32][24] -> [24][32]
      int r2 = i / 24, ch = i % 24;
      s4[1024 + ch*32 + r2] = g4[3328 + i];                       // fb f4 3328..4095
    }
    if (tid < 256) s4[1792 + tid] = g4[1792 + tid];               // Wx chunks 28-31 (fb f4 1792..2047)
  }
  const int wv = tid >> 6, l = tid & 63;
  const int r = l & 31, lh = l >> 5;
  const int e = blockIdx.x * 4 + wv;           // this wave's element
  float* xu = &sXU[wv][0];

  // Wx chunks 0..27, row l: 28 f4 = 112 regs (loaded once, coalesced, asm-pinned)
  float4 wx[28];
  {
    const float4* WxG = (const float4*)fb;
    #pragma unroll
    for (int c = 0; c < 28; ++c) wx[c] = WxG[(c << 6) + l];
  }
  // D11' row r (strict lower, K/Lam-scaled): 32 regs, asm-pinned
  float d11[32];
  {
    const float4* DG = (const float4*)(fb + 12288);
    #pragma unroll
    for (int c = 0; c < 8; ++c) {
      float4 dv = DG[r*8 + c];
      d11[4*c+0] = dv.x; d11[4*c+1] = dv.y; d11[4*c+2] = dv.z; d11[4*c+3] = dv.w;
    }
  }
  // Opaque-pin (scalar ties only): forbids remat/load-sinking.
  #pragma unroll
  for (int c = 0; c < 28; ++c) {
    PIN(wx[c].x); PIN(wx[c].y); PIN(wx[c].z); PIN(wx[c].w);
  }
  #pragma unroll
  for (int j = 0; j < 32; ++j) PIN(d11[j]);

  // x0 and u(t=0)
  xu[l] = x0[(size_t)e*64 + l];
  xu[96 + r] = u_in[(size_t)e*8192 + r];       // both halves write same value
  __syncthreads();   // weights staged (once, outside t-loop)

  const float4* xu4  = (const float4*)xu;      // 33 f4: x 0-15 | w 16-23 | u 24-31
  const float4* WyT4 = (const float4*)sW;              // [(ch<<5)+r]
  const float4* WaT4 = (const float4*)sW + 1024;       // [(lh*12+c)*32 + r]
  const float4* sWx4 = (const float4*)sW + 1792;       // [(c-28)*64 + l]
  const float* uG = u_in + (size_t)e * 8192;
  float* oG = out + (size_t)e * 8192;

#define FMA4(A, W, XV) \
  A.x = fmaf(W.x, XV.x, A.x); A.y = fmaf(W.y, XV.y, A.y); \
  A.z = fmaf(W.z, XV.z, A.z); A.w = fmaf(W.w, XV.w, A.w);

  for (int t = 0; t < 256; ++t) {
    const int tn = (t < 255) ? (t + 1) : 255;
    float unext = uG[tn*32 + r];               // prefetch u_{t+1}
    // ---- A: a_r (K-scaled), k-split across halves, combine via shfl ----
    float4 sA = make_float4(0.f, 0.f, 0.f, 0.f);
    #pragma unroll
    for (int c = 0; c < 12; ++c) {
      int ch = lh*12 + c;
      int xi = (ch < 16) ? ch : (ch + 8);      // u chunks at f4 24..31
      float4 xv = xu4[xi]; float4 wv4 = WaT4[ch*32 + r];
      FMA4(sA, wv4, xv)
    }
    float a = hsum4(sA);
    a += __shfl_xor(a, 32);                    // all 64 lanes: K*a for row r
    // ---- X partial: x chunks (regs) + u chunks (regs 24-27, LDS 28-31) ----
    float4 P4 = make_float4(0.f, 0.f, 0.f, 0.f);
    #pragma unroll
    for (int c = 0; c < 16; ++c) { float4 xv = xu4[c]; FMA4(P4, wx[c], xv) }
    #pragma unroll
    for (int c = 24; c < 28; ++c) { float4 xv = xu4[c]; FMA4(P4, wx[c], xv) }
    #pragma unroll
    for (int c = 28; c < 32; ++c) { float4 xv = xu4[c]; float4 wv4 = sWx4[((c - 28) << 6) + l]; FMA4(P4, wv4, xv) }
    // ---- Y partial: D22.u chunks (lh0: 24..27, lh1: 28..31) ----
    float4 Q4 = make_float4(0.f, 0.f, 0.f, 0.f);
    #pragma unroll
    for (int c = 0; c < 4; ++c) {
      int ch = 24 + lh*4 + c;
      float4 xv = xu4[ch]; float4 wv4 = WyT4[(ch << 5) + r];
      FMA4(Q4, wv4, xv)
    }
    // ---- serial tanh forward-substitution (6-op step, exp2 domain) ----
    float v = a;
    #pragma unroll
    for (int j = 0; j < 31; ++j) {
      float E = __builtin_exp2f(v);
      float w = fmaf(-2.f, frcp(E + 1.f), 1.f);
      float b = __int_as_float(__builtin_amdgcn_readlane(__float_as_int(w), j));
      v = fmaf(d11[j], b, v);
    }
    float Ef = __builtin_exp2f(v);
    float myw = fmaf(-2.f, frcp(Ef + 1.f), 1.f);
    xu[64 + r] = myw;                          // both halves same value
    // ---- X final: w chunks 16..23 (regs), then store xn ----
    #pragma unroll
    for (int c = 16; c < 24; ++c) { float4 xv = xu4[c]; FMA4(P4, wx[c], xv) }
    xu[l] = hsum4(P4);                         // xn row l
    // ---- Y final: chunks lh*12 .. lh*12+11 (xn + w), combine via shfl ----
    #pragma unroll
    for (int c = 0; c < 12; ++c) {
      int ch = lh*12 + c;
      float4 xv = xu4[ch]; float4 wv4 = WyT4[(ch << 5) + r];
      FMA4(Q4, wv4, xv)
    }
    float y = hsum4(Q4);
    y += __shfl_xor(y, 32);
    if (l < 32) oG[t*32 + l] = y;              // contiguous 128 B
    xu[96 + r] = unext;                        // u_{t+1} (u_t fully consumed)
  }
#undef FMA4
}
#undef PIN

// ================= launch =================
extern "C" void kernel_launch(void* const* d_in, const int* in_sizes, int n_in,
                              void* d_out, int out_size, void* d_ws, size_t ws_size,
                              hipStream_t stream)
{
  const float* u_in = (const float*)d_in[0];
  const float* x0   = (const float*)d_in[1];
  const float* X    = (const float*)d_in[2];
  const float* Y    = (const float*)d_in[3];
  const float* B2   = (const float*)d_in[4];
  const float* C2   = (const float*)d_in[5];
  const float* D12  = (const float*)d_in[6];
  const float* L    = (const float*)d_in[7];   // D22_L
  const float* U    = (const float*)d_in[8];   // D22_U
  const float* D21  = (const float*)d_in[9];
  const float* gam  = (const float*)d_in[10];
  double* wsd = (double*)d_ws;
  float* out = (float*)d_out;

  hipLaunchKernelGGL(prep1, dim3(1), dim3(1024), 0, stream, B2, C2, D12, L, U, D21, gam, wsd);
  hipLaunchKernelGGL(prep2, dim3(100), dim3(256), 0, stream, X, C2, D21, wsd);
  hipLaunchKernelGGL(prep3, dim3(1), dim3(1024), 0, stream, Y, B2, C2, D12, D21, wsd);
  hipLaunchKernelGGL(ren_main, dim3(512), dim3(256), 0, stream, u_in, x0, wsd, out);
}